// Round 6
// baseline (146.543 us; speedup 1.0000x reference)
//
#include <hip/hip_runtime.h>
#include <math.h>

#define KK 32
#define CC 256

// ---------------------------------------------------------------------------
// Kernel 1: blocks 0..255 = per-(b,m) stats (adj); blocks 256..767 = A rows.
// Stats: stage x in LDS, means, center, cov upper-tri 2x2 tiles (BIT-EXACT
// sequential fma chain — the adj>0 mask must match ref), adj -> out region.
// A: A[o,k] = 0.5*rowsum_k(W1 row o) + colsum_k - 0.5*W1[o,33k] so that
// W1 @ p == A @ mean (pooled_ij = (i==j)? m_i : 0.5*m_i + m_j).
// ---------------------------------------------------------------------------
__global__ __launch_bounds__(256) void stats_a_kernel(
    const float* __restrict__ x, const float* __restrict__ W1,
    float* __restrict__ A_ws, float* __restrict__ adj_out)
{
    __shared__ float xs[KK][258];
    __shared__ float part8[256];
    __shared__ float meanv[KK];
    __shared__ float covm[KK][KK + 1];
    __shared__ float stdv[KK];

    const int t = threadIdx.x;

    if (blockIdx.x >= 256) {
        // ---------------- A rows: one W1 row per block ----------------
        float* rowlds = &xs[0][0];                // reuse (1056 <= 32*258)
        const int o = blockIdx.x - 256;           // 0..511
        if (t < 64) {
            const float* wr = W1 + (size_t)o * 1024;
            #pragma unroll
            for (int u = 0; u < 4; ++u) {
                const int e = t * 16 + u * 4;
                const float4 v = *(const float4*)(wr + e);
                const int f = (e >> 5) * 33 + (e & 31);
                rowlds[f] = v.x; rowlds[f + 1] = v.y;
                rowlds[f + 2] = v.z; rowlds[f + 3] = v.w;
            }
        }
        __syncthreads();
        if (t < 32) {
            float rs = 0.f, cs = 0.f;
            #pragma unroll
            for (int j = 0; j < 32; ++j) rs += rowlds[t * 33 + j];
            #pragma unroll
            for (int i = 0; i < 32; ++i) cs += rowlds[i * 33 + t];
            A_ws[o * 32 + t] = 0.5f * rs + cs - 0.5f * rowlds[t * 34];
        }
        return;
    }

    // ---------------- stats ----------------
    const int bm = blockIdx.x;            // 0..255
    const float* xp = x + (size_t)bm * (KK * CC);

    #pragma unroll
    for (int s = 0; s < 8; ++s) {
        const int e = s * 1024 + t * 4;
        const float4 v = *(const float4*)(xp + e);
        const int i = e >> 8, col = e & 255;
        xs[i][col] = v.x; xs[i][col + 1] = v.y;
        xs[i][col + 2] = v.z; xs[i][col + 3] = v.w;
    }
    __syncthreads();
    {
        const int i = t >> 3, part = t & 7;
        float s = 0.f;
        const int c0 = part * 32;
        #pragma unroll
        for (int c = 0; c < 32; ++c) s += xs[i][c0 + c];
        part8[t] = s;
    }
    __syncthreads();
    if (t < KK) {
        float s = 0.f;
        #pragma unroll
        for (int k = 0; k < 8; ++k) s += part8[t * 8 + k];
        meanv[t] = s * (1.0f / CC);
    }
    __syncthreads();
    {
        const int r = t >> 3, c0 = (t & 7) * 32;
        const float mv = meanv[r];
        #pragma unroll
        for (int c = 0; c < 32; ++c) xs[r][c0 + c] -= mv;
    }
    __syncthreads();
    if (t < 136) {
        int rem = t, r = 0;
        while (rem >= 16 - r) { rem -= 16 - r; ++r; }
        const int ti = r, tj = r + rem;
        const int i0 = 2 * ti, i1 = i0 + 1, j0 = 2 * tj, j1 = j0 + 1;
        float c00 = 0.f, c01 = 0.f, c10 = 0.f, c11 = 0.f;
        for (int c = 0; c < CC; c += 2) {
            const float2 a0 = *(const float2*)&xs[i0][c];
            const float2 a1 = *(const float2*)&xs[i1][c];
            const float2 b0 = *(const float2*)&xs[j0][c];
            const float2 b1 = *(const float2*)&xs[j1][c];
            // sequential fma chain per accumulator — bit-exact vs R5
            c00 += a0.x * b0.x; c00 += a0.y * b0.y;
            c01 += a0.x * b1.x; c01 += a0.y * b1.y;
            c10 += a1.x * b0.x; c10 += a1.y * b0.y;
            c11 += a1.x * b1.x; c11 += a1.y * b1.y;
        }
        c00 *= (1.0f / (CC - 1)); c01 *= (1.0f / (CC - 1));
        c10 *= (1.0f / (CC - 1)); c11 *= (1.0f / (CC - 1));
        covm[i0][j0] = c00; covm[i0][j1] = c01;
        covm[i1][j0] = c10; covm[i1][j1] = c11;
        covm[j0][i0] = c00; covm[j1][i0] = c01;
        covm[j0][i1] = c10; covm[j1][i1] = c11;
    }
    __syncthreads();
    if (t < KK) stdv[t] = sqrtf(covm[t][t]);
    __syncthreads();
    #pragma unroll
    for (int k = 0; k < 4; ++k) {
        const int pair = t + k * 256;
        const int i = pair >> 5, j = pair & 31;
        adj_out[(size_t)bm * 1024 + pair] = covm[i][j] / (stdv[i] * stdv[j]);
    }
}

// ---------------------------------------------------------------------------
// Kernel 2: everything after stats, self-contained per (b, m-pair).
// Grid (32 m-pairs, 4 b), 256 threads, ~80 KB LDS (2 blocks/CU).
//  A: stage x for both m's; recompute means (loose path — only feeds h/e).
//  B: h[c][mm] = gelu(A[c,:] . mu[:,mm])  (512 x 2, in LDS)
//  C: e[o][mm] = sigmoid(W2[o,:] . h[:,mm]); mask with adj>0 -> att LDS.
//     W2 streamed from L2 per block (4 rows/thread, rows lane-consecutive).
//  D: per-row softmax (same sequential chain as R5) + att @ x -> out.
// ---------------------------------------------------------------------------
__global__ __launch_bounds__(256) void fused_tail_kernel(
    const float* __restrict__ x, const float* __restrict__ W2,
    const float* __restrict__ A_ws, const float* __restrict__ adj,
    float* __restrict__ out)
{
    __shared__ float xs[2][KK][260];       // 66.6 KB
    __shared__ float att[2][KK][KK + 1];   // 8.45 KB
    __shared__ float hsh[512][2];          // 4 KB
    __shared__ float mu[KK][2];
    __shared__ float part4[64][4];

    const int t   = threadIdx.x;
    const int b   = blockIdx.y;
    const int m0  = blockIdx.x;            // 0..31 (pair index)
    const int bm0 = b * 64 + m0 * 2;

    // ---- stage x for mm = 0,1 ----
    #pragma unroll
    for (int mm = 0; mm < 2; ++mm) {
        const float* xp = x + (size_t)(bm0 + mm) * (KK * CC);
        #pragma unroll
        for (int s = 0; s < 8; ++s) {
            const int e = s * 1024 + t * 4;
            const float4 v = *(const float4*)(xp + e);
            *(float4*)&xs[mm][e >> 8][e & 255] = v;
        }
    }
    __syncthreads();

    // ---- means (loose path: feeds only h/e) ----
    {
        const int pair = t >> 2, part = t & 3;     // pair: mm*32+i
        const int mm = pair >> 5, i = pair & 31;
        float s = 0.f;
        const int c0 = part * 64;
        #pragma unroll
        for (int c = 0; c < 64; ++c) s += xs[mm][i][c0 + c];
        part4[pair][part] = s;
    }
    __syncthreads();
    if (t < 64) {
        const int mm = t >> 5, i = t & 31;
        mu[i][mm] = (part4[t][0] + part4[t][1] + part4[t][2] + part4[t][3])
                    * (1.0f / CC);
    }
    __syncthreads();

    // ---- h = gelu(A @ mu): thread t does c = t, t+256 ----
    #pragma unroll
    for (int cq = 0; cq < 2; ++cq) {
        const int c = t + cq * 256;
        const float* Ar = A_ws + (size_t)c * 32;
        float a0 = 0.f, a1 = 0.f;
        #pragma unroll
        for (int k = 0; k < 32; ++k) {
            const float av = Ar[k];
            a0 += av * mu[k][0];
            a1 += av * mu[k][1];
        }
        hsh[c][0] = 0.5f * a0 * (1.0f + erff(a0 * 0.70710678118654752f));
        hsh[c][1] = 0.5f * a1 * (1.0f + erff(a1 * 0.70710678118654752f));
    }
    __syncthreads();

    // ---- e = sigmoid(W2 @ h), masked into att ----
    {
        float acc[4][2];
        #pragma unroll
        for (int q = 0; q < 4; ++q) { acc[q][0] = 0.f; acc[q][1] = 0.f; }
        for (int c = 0; c < 512; c += 4) {
            const float h00 = hsh[c][0],     h01 = hsh[c][1];
            const float h10 = hsh[c + 1][0], h11 = hsh[c + 1][1];
            const float h20 = hsh[c + 2][0], h21 = hsh[c + 2][1];
            const float h30 = hsh[c + 3][0], h31 = hsh[c + 3][1];
            #pragma unroll
            for (int q = 0; q < 4; ++q) {
                const float4 w = *(const float4*)(W2 + (size_t)(t + 256 * q) * 512 + c);
                acc[q][0] += w.x * h00; acc[q][0] += w.y * h10;
                acc[q][0] += w.z * h20; acc[q][0] += w.w * h30;
                acc[q][1] += w.x * h01; acc[q][1] += w.y * h11;
                acc[q][1] += w.z * h21; acc[q][1] += w.w * h31;
            }
        }
        #pragma unroll
        for (int q = 0; q < 4; ++q) {
            const int o = t + 256 * q;
            #pragma unroll
            for (int mm = 0; mm < 2; ++mm) {
                const float ev = 1.0f / (1.0f + expf(-acc[q][mm]));
                const float aj = adj[(size_t)(bm0 + mm) * 1024 + o];
                att[mm][o >> 5][o & 31] = (aj > 0.f) ? ev : -INFINITY;
            }
        }
    }
    __syncthreads();

    // ---- softmax rows (same sequential chain as R5) ----
    if (t < 64) {
        const int mm = t >> 5, i = t & 31;
        float mx = -INFINITY;
        #pragma unroll
        for (int j = 0; j < KK; ++j) mx = fmaxf(mx, att[mm][i][j]);
        float s = 0.f;
        #pragma unroll
        for (int j = 0; j < KK; ++j) {
            const float v = expf(att[mm][i][j] - mx);
            att[mm][i][j] = v;
            s += v;
        }
        const float inv = 1.0f / s;
        #pragma unroll
        for (int j = 0; j < KK; ++j) att[mm][i][j] *= inv;
    }
    __syncthreads();

    // ---- out = att @ x : 128 threads per mm; 8 i x 2 float4-chunks each ----
    {
        const int mm = t >> 7;
        const int tt = t & 127;
        const int c8 = tt & 31, iq = tt >> 5;      // iq 0..3 -> i = iq*8+r
        const int cA = 4 * c8, cB = 128 + 4 * c8;
        float4 accA[8], accB[8];
        #pragma unroll
        for (int r = 0; r < 8; ++r) {
            accA[r] = make_float4(0.f, 0.f, 0.f, 0.f);
            accB[r] = make_float4(0.f, 0.f, 0.f, 0.f);
        }
        const int i0 = iq * 8;
        for (int j = 0; j < KK; ++j) {
            const float4 xa = *(const float4*)&xs[mm][j][cA];
            const float4 xb = *(const float4*)&xs[mm][j][cB];
            #pragma unroll
            for (int r = 0; r < 8; ++r) {
                const float av = att[mm][i0 + r][j];
                accA[r].x += av * xa.x; accA[r].y += av * xa.y;
                accA[r].z += av * xa.z; accA[r].w += av * xa.w;
                accB[r].x += av * xb.x; accB[r].y += av * xb.y;
                accB[r].z += av * xb.z; accB[r].w += av * xb.w;
            }
        }
        float* op = out + (size_t)(bm0 + mm) * (KK * CC);
        #pragma unroll
        for (int r = 0; r < 8; ++r) {
            *(float4*)(op + (size_t)(i0 + r) * CC + cA) = accA[r];
            *(float4*)(op + (size_t)(i0 + r) * CC + cB) = accB[r];
        }
    }
}

extern "C" void kernel_launch(void* const* d_in, const int* in_sizes, int n_in,
                              void* d_out, int out_size, void* d_ws, size_t ws_size,
                              hipStream_t stream) {
    const float* x  = (const float*)d_in[0];   // (4,64,32,256)
    const float* W1 = (const float*)d_in[1];   // (512,1024)
    const float* W2 = (const float*)d_in[2];   // (1024,512)
    float* out     = (float*)d_out;                       // 2,097,152 floats
    float* adj_out = out + (size_t)4 * 64 * 32 * 256;     // +262,144 floats

    float* A_ws = (float*)d_ws;                // 512*32 = 16,384 floats

    stats_a_kernel<<<768, 256, 0, stream>>>(x, W1, A_ws, adj_out);
    fused_tail_kernel<<<dim3(32, 4), 256, 0, stream>>>(x, W2, A_ws, adj_out, out);
}

// Round 7
// 142.966 us; speedup vs baseline: 1.0250x; 1.0250x over previous
//
#include <hip/hip_runtime.h>
#include <math.h>

#define KK 32
#define CC 256

// ---------------------------------------------------------------------------
// Kernel 1: blocks 0..255 = per-(b,m) stats (adj + means); 256..767 = A rows.
// Stats: stage x in LDS, means (-> mean_ws), center, cov upper-tri 2x2 tiles
// (BIT-EXACT sequential fma chain — the adj>0 mask must match ref), adj out.
// A: A[o,k] = 0.5*rowsum_k(W1 row o) + colsum_k - 0.5*W1[o,33k] so that
// W1 @ p == A @ mean (pooled_ij = (i==j)? m_i : 0.5*m_i + m_j).
// ---------------------------------------------------------------------------
__global__ __launch_bounds__(256) void stats_a_kernel(
    const float* __restrict__ x, const float* __restrict__ W1,
    float* __restrict__ A_ws, float* __restrict__ mean_ws,
    float* __restrict__ adj_out)
{
    __shared__ float xs[KK][258];
    __shared__ float part8[256];
    __shared__ float meanv[KK];
    __shared__ float covm[KK][KK + 1];
    __shared__ float stdv[KK];

    const int t = threadIdx.x;

    if (blockIdx.x >= 256) {
        // ---------------- A rows: one W1 row per block ----------------
        float* rowlds = &xs[0][0];                // reuse (1056 <= 32*258)
        const int o = blockIdx.x - 256;           // 0..511
        if (t < 64) {
            const float* wr = W1 + (size_t)o * 1024;
            #pragma unroll
            for (int u = 0; u < 4; ++u) {
                const int e = t * 16 + u * 4;
                const float4 v = *(const float4*)(wr + e);
                const int f = (e >> 5) * 33 + (e & 31);
                rowlds[f] = v.x; rowlds[f + 1] = v.y;
                rowlds[f + 2] = v.z; rowlds[f + 3] = v.w;
            }
        }
        __syncthreads();
        if (t < 32) {
            float rs = 0.f, cs = 0.f;
            #pragma unroll
            for (int j = 0; j < 32; ++j) rs += rowlds[t * 33 + j];
            #pragma unroll
            for (int i = 0; i < 32; ++i) cs += rowlds[i * 33 + t];
            A_ws[o * 32 + t] = 0.5f * rs + cs - 0.5f * rowlds[t * 34];
        }
        return;
    }

    // ---------------- stats ----------------
    const int bm = blockIdx.x;            // 0..255
    const int b  = bm >> 6, m = bm & 63;
    const float* xp = x + (size_t)bm * (KK * CC);

    #pragma unroll
    for (int s = 0; s < 8; ++s) {
        const int e = s * 1024 + t * 4;
        const float4 v = *(const float4*)(xp + e);
        const int i = e >> 8, col = e & 255;
        xs[i][col] = v.x; xs[i][col + 1] = v.y;
        xs[i][col + 2] = v.z; xs[i][col + 3] = v.w;
    }
    __syncthreads();
    {
        const int i = t >> 3, part = t & 7;
        float s = 0.f;
        const int c0 = part * 32;
        #pragma unroll
        for (int c = 0; c < 32; ++c) s += xs[i][c0 + c];
        part8[t] = s;
    }
    __syncthreads();
    if (t < KK) {
        float s = 0.f;
        #pragma unroll
        for (int k = 0; k < 8; ++k) s += part8[t * 8 + k];
        meanv[t] = s * (1.0f / CC);
        mean_ws[(size_t)(b * 32 + t) * 64 + m] = meanv[t];
    }
    __syncthreads();
    {
        const int r = t >> 3, c0 = (t & 7) * 32;
        const float mv = meanv[r];
        #pragma unroll
        for (int c = 0; c < 32; ++c) xs[r][c0 + c] -= mv;
    }
    __syncthreads();
    if (t < 136) {
        int rem = t, r = 0;
        while (rem >= 16 - r) { rem -= 16 - r; ++r; }
        const int ti = r, tj = r + rem;
        const int i0 = 2 * ti, i1 = i0 + 1, j0 = 2 * tj, j1 = j0 + 1;
        float c00 = 0.f, c01 = 0.f, c10 = 0.f, c11 = 0.f;
        for (int c = 0; c < CC; c += 2) {
            const float2 a0 = *(const float2*)&xs[i0][c];
            const float2 a1 = *(const float2*)&xs[i1][c];
            const float2 b0 = *(const float2*)&xs[j0][c];
            const float2 b1 = *(const float2*)&xs[j1][c];
            // sequential fma chain per accumulator — bit-exact vs R5
            c00 += a0.x * b0.x; c00 += a0.y * b0.y;
            c01 += a0.x * b1.x; c01 += a0.y * b1.y;
            c10 += a1.x * b0.x; c10 += a1.y * b0.y;
            c11 += a1.x * b1.x; c11 += a1.y * b1.y;
        }
        c00 *= (1.0f / (CC - 1)); c01 *= (1.0f / (CC - 1));
        c10 *= (1.0f / (CC - 1)); c11 *= (1.0f / (CC - 1));
        covm[i0][j0] = c00; covm[i0][j1] = c01;
        covm[i1][j0] = c10; covm[i1][j1] = c11;
        covm[j0][i0] = c00; covm[j1][i0] = c01;
        covm[j0][i1] = c10; covm[j1][i1] = c11;
    }
    __syncthreads();
    if (t < KK) stdv[t] = sqrtf(covm[t][t]);
    __syncthreads();
    #pragma unroll
    for (int k = 0; k < 4; ++k) {
        const int pair = t + k * 256;
        const int i = pair >> 5, j = pair & 31;
        adj_out[(size_t)bm * 1024 + pair] = covm[i][j] / (stdv[i] * stdv[j]);
    }
}

// ---------------------------------------------------------------------------
// Kernel 2 (mlp1+mlp2 fused): grid (64 o-tiles, 4 b), block 256 (4 waves).
// Each block: stage mu[32][64] (8 KB), then for each 256-c half:
//   - waves cooperatively compute hsh[c_local][m] = gelu(A[c,:].mu[:,m])
//     (A row wave-uniform from L2; mr[32] in registers; k-ascending chain)
//   - stage W2s[16][256] tile (coalesced), then R5-mlp2-style broadcast
//     accumulation (c-ascending across ordered halves -> bit-exact e chain)
// e_ws layout [b][m][o], one float4 store/thread (same as R5).
// LDS: 64 + 16 + 8 = 88 KB -> 1 block/CU, 256 blocks = full chip.
// ---------------------------------------------------------------------------
__global__ __launch_bounds__(256) void mlp_fused_kernel(
    const float* __restrict__ A_ws, const float* __restrict__ mean_ws,
    const float* __restrict__ W2, float* __restrict__ e_ws)
{
    __shared__ float hsh[256][64];     // 64 KB  [c_local][m]
    __shared__ float W2s[16][256];     // 16 KB
    __shared__ float mu[32][64];       // 8 KB   [k][m]

    const int t  = threadIdx.x;
    const int m  = t & 63, ow = t >> 6;
    const int b  = blockIdx.y;
    const int ob = blockIdx.x * 16;
    const int ol = ow * 4;

    // stage mu (coalesced; mean_ws is [(b*32+k)*64 + m])
    #pragma unroll
    for (int u = 0; u < 8; ++u) {
        const int e = t + u * 256;           // = k*64 + m over all (k,m)
        mu[e >> 6][e & 63] = mean_ws[(size_t)(b * 32) * 64 + e];
    }
    __syncthreads();

    // per-thread register copy of its mean column (as R5 mlp1's mr[])
    float mr[32];
    #pragma unroll
    for (int k = 0; k < 32; ++k) mr[k] = mu[k][m];

    float acc[4] = {0.f, 0.f, 0.f, 0.f};

    #pragma unroll
    for (int half = 0; half < 2; ++half) {
        // ---- h for this half: wave ow covers c_local in [ow*64, ow*64+64) ----
        for (int i = 0; i < 64; ++i) {
            const int cl = ow * 64 + i;
            const int c  = half * 256 + cl;
            const float* Ar = A_ws + (size_t)c * 32;   // wave-uniform row
            float a = 0.f;
            #pragma unroll
            for (int k = 0; k < 32; ++k) a += Ar[k] * mr[k];  // k-ascending
            hsh[cl][m] = 0.5f * a * (1.0f + erff(a * 0.70710678118654752f));
        }
        // ---- stage W2s[16][256] for this half (coalesced float4) ----
        {
            const float* src = W2 + (size_t)ob * 512 + half * 256;
            #pragma unroll
            for (int u = 0; u < 4; ++u) {
                const int e4 = t + u * 256;        // 0..1023
                const int row = e4 >> 6, c4 = (e4 & 63) * 4;
                *(float4*)&W2s[row][c4] =
                    *(const float4*)(src + (size_t)row * 512 + c4);
            }
        }
        __syncthreads();
        // ---- accumulate (R5 mlp2 inner, c-ascending within half) ----
        for (int cl = 0; cl < 256; cl += 4) {
            const float hv0 = hsh[cl][m];
            const float hv1 = hsh[cl + 1][m];
            const float hv2 = hsh[cl + 2][m];
            const float hv3 = hsh[cl + 3][m];
            #pragma unroll
            for (int q = 0; q < 4; ++q) {
                const float4 w = *(const float4*)&W2s[ol + q][cl];  // broadcast
                acc[q] += w.x * hv0;
                acc[q] += w.y * hv1;
                acc[q] += w.z * hv2;
                acc[q] += w.w * hv3;
            }
        }
        __syncthreads();   // before next half overwrites hsh/W2s
    }

    float4 sv;
    sv.x = 1.0f / (1.0f + expf(-acc[0]));
    sv.y = 1.0f / (1.0f + expf(-acc[1]));
    sv.z = 1.0f / (1.0f + expf(-acc[2]));
    sv.w = 1.0f / (1.0f + expf(-acc[3]));
    *(float4*)&e_ws[(size_t)(b * 64 + m) * 1024 + ob + ol] = sv;
}

// ---------------------------------------------------------------------------
// Kernel 3: masked softmax (mask adj>0) + att @ x.  256 blocks (b,m).
// e and adj reads fully-coalesced float4 (e layout [b][m][o]).
// ---------------------------------------------------------------------------
__global__ __launch_bounds__(256) void softmax_out_kernel(
    const float* __restrict__ x, const float* __restrict__ e_ws,
    const float* __restrict__ adj, float* __restrict__ out)
{
    __shared__ float xs[KK][260];
    __shared__ float att[KK][KK + 1];
    const int bm = blockIdx.x;
    const int b  = bm >> 6, m = bm & 63;
    const int t  = threadIdx.x;
    const float* xp = x + (size_t)bm * (KK * CC);

    #pragma unroll
    for (int s = 0; s < 8; ++s) {
        const int e = s * 1024 + t * 4;
        const float4 v = *(const float4*)(xp + e);
        *(float4*)&xs[e >> 8][e & 255] = v;
    }
    {
        const int p0 = 4 * t;
        const float4 ev4 = *(const float4*)&e_ws[(size_t)(b * 64 + m) * 1024 + p0];
        const float4 aj4 = *(const float4*)&adj[(size_t)bm * 1024 + p0];
        const int i = p0 >> 5, j0 = p0 & 31;
        att[i][j0]     = (aj4.x > 0.f) ? ev4.x : -INFINITY;
        att[i][j0 + 1] = (aj4.y > 0.f) ? ev4.y : -INFINITY;
        att[i][j0 + 2] = (aj4.z > 0.f) ? ev4.z : -INFINITY;
        att[i][j0 + 3] = (aj4.w > 0.f) ? ev4.w : -INFINITY;
    }
    __syncthreads();
    if (t < KK) {
        float mx = -INFINITY;
        #pragma unroll
        for (int j = 0; j < KK; ++j) mx = fmaxf(mx, att[t][j]);
        float s = 0.f;
        #pragma unroll
        for (int j = 0; j < KK; ++j) {
            const float v = expf(att[t][j] - mx);
            att[t][j] = v;
            s += v;
        }
        const float inv = 1.0f / s;
        #pragma unroll
        for (int j = 0; j < KK; ++j) att[t][j] *= inv;
    }
    __syncthreads();

    const int c8 = t & 31, iq = t >> 5;
    const int i0 = iq * 4;
    const int cA = 4 * c8, cB = 128 + 4 * c8;
    float4 accA[4], accB[4];
    #pragma unroll
    for (int r = 0; r < 4; ++r) {
        accA[r] = make_float4(0.f, 0.f, 0.f, 0.f);
        accB[r] = make_float4(0.f, 0.f, 0.f, 0.f);
    }
    for (int j = 0; j < KK; ++j) {
        const float4 xa = *(const float4*)&xs[j][cA];
        const float4 xb = *(const float4*)&xs[j][cB];
        #pragma unroll
        for (int r = 0; r < 4; ++r) {
            const float av = att[i0 + r][j];
            accA[r].x += av * xa.x; accA[r].y += av * xa.y;
            accA[r].z += av * xa.z; accA[r].w += av * xa.w;
            accB[r].x += av * xb.x; accB[r].y += av * xb.y;
            accB[r].z += av * xb.z; accB[r].w += av * xb.w;
        }
    }
    float* op = out + (size_t)bm * (KK * CC);
    #pragma unroll
    for (int r = 0; r < 4; ++r) {
        *(float4*)(op + (size_t)(i0 + r) * CC + cA) = accA[r];
        *(float4*)(op + (size_t)(i0 + r) * CC + cB) = accB[r];
    }
}

extern "C" void kernel_launch(void* const* d_in, const int* in_sizes, int n_in,
                              void* d_out, int out_size, void* d_ws, size_t ws_size,
                              hipStream_t stream) {
    const float* x  = (const float*)d_in[0];   // (4,64,32,256)
    const float* W1 = (const float*)d_in[1];   // (512,1024)
    const float* W2 = (const float*)d_in[2];   // (1024,512)
    float* out     = (float*)d_out;                       // 2,097,152 floats
    float* adj_out = out + (size_t)4 * 64 * 32 * 256;     // +262,144 floats

    float* A_ws    = (float*)d_ws;                 // 512*32  =  16,384
    float* mean_ws = A_ws + 16384;                 // 4*32*64 =   8,192
    float* e_ws    = mean_ws + 8192;               // 4*64*1024 = 262,144

    stats_a_kernel<<<768, 256, 0, stream>>>(x, W1, A_ws, mean_ws, adj_out);
    mlp_fused_kernel<<<dim3(64, 4), 256, 0, stream>>>(A_ws, mean_ws, W2, e_ws);
    softmax_out_kernel<<<256, 256, 0, stream>>>(x, e_ws, adj_out, out);
}

// Round 8
// 108.425 us; speedup vs baseline: 1.3516x; 1.3186x over previous
//
#include <hip/hip_runtime.h>
#include <math.h>

#define KK 32
#define CC 256

// ---------------------------------------------------------------------------
// Kernel 1: blocks 0..255 = per-(b,m) stats (adj + means); 256..767 = A rows.
// Stats: stage x in LDS (stride 260, float4-aligned), means -> mean_ws,
// center, cov upper-tri 2x2 tiles via float4 reads (c-ascending fma chain —
// BIT-EXACT vs R5; the adj>0 mask is knife-edge), adj -> out region.
// A: A[o,k] = 0.5*rowsum_k(W1 row o) + colsum_k - 0.5*W1[o,33k] so that
// W1 @ p == A @ mean (pooled_ij = (i==j)? m_i : 0.5*m_i + m_j).
// ---------------------------------------------------------------------------
__global__ __launch_bounds__(256) void stats_a_kernel(
    const float* __restrict__ x, const float* __restrict__ W1,
    float* __restrict__ A_ws, float* __restrict__ mean_ws,
    float* __restrict__ adj_out)
{
    __shared__ float xs[KK][260];
    __shared__ float part8[256];
    __shared__ float meanv[KK];
    __shared__ float covm[KK][KK + 1];
    __shared__ float stdv[KK];

    const int t = threadIdx.x;

    if (blockIdx.x >= 256) {
        // ---------------- A rows: one W1 row per block ----------------
        float* rowlds = &xs[0][0];                // reuse (1056 <= 32*260)
        const int o = blockIdx.x - 256;           // 0..511
        if (t < 64) {
            const float* wr = W1 + (size_t)o * 1024;
            #pragma unroll
            for (int u = 0; u < 4; ++u) {
                const int e = t * 16 + u * 4;
                const float4 v = *(const float4*)(wr + e);
                const int f = (e >> 5) * 33 + (e & 31);
                rowlds[f] = v.x; rowlds[f + 1] = v.y;
                rowlds[f + 2] = v.z; rowlds[f + 3] = v.w;
            }
        }
        __syncthreads();
        if (t < 32) {
            float rs = 0.f, cs = 0.f;
            #pragma unroll
            for (int j = 0; j < 32; ++j) rs += rowlds[t * 33 + j];
            #pragma unroll
            for (int i = 0; i < 32; ++i) cs += rowlds[i * 33 + t];
            A_ws[o * 32 + t] = 0.5f * rs + cs - 0.5f * rowlds[t * 34];
        }
        return;
    }

    // ---------------- stats ----------------
    const int bm = blockIdx.x;            // 0..255
    const int b  = bm >> 6, m = bm & 63;
    const float* xp = x + (size_t)bm * (KK * CC);

    #pragma unroll
    for (int s = 0; s < 8; ++s) {
        const int e = s * 1024 + t * 4;
        const float4 v = *(const float4*)(xp + e);
        *(float4*)&xs[e >> 8][e & 255] = v;    // (260*i + col) % 4 == 0
    }
    __syncthreads();
    {
        const int i = t >> 3, part = t & 7;
        float s = 0.f;
        const int c0 = part * 32;
        #pragma unroll
        for (int c = 0; c < 32; ++c) s += xs[i][c0 + c];
        part8[t] = s;
    }
    __syncthreads();
    if (t < KK) {
        float s = 0.f;
        #pragma unroll
        for (int k = 0; k < 8; ++k) s += part8[t * 8 + k];
        meanv[t] = s * (1.0f / CC);
        mean_ws[(size_t)(b * 32 + t) * 64 + m] = meanv[t];
    }
    __syncthreads();
    {
        const int r = t >> 3, c0 = (t & 7) * 32;
        const float mv = meanv[r];
        #pragma unroll
        for (int c = 0; c < 32; ++c) xs[r][c0 + c] -= mv;
    }
    __syncthreads();
    if (t < 136) {
        int rem = t, r = 0;
        while (rem >= 16 - r) { rem -= 16 - r; ++r; }
        const int ti = r, tj = r + rem;
        const int i0 = 2 * ti, i1 = i0 + 1, j0 = 2 * tj, j1 = j0 + 1;
        float c00 = 0.f, c01 = 0.f, c10 = 0.f, c11 = 0.f;
        for (int c = 0; c < CC; c += 4) {
            const float4 a0 = *(const float4*)&xs[i0][c];
            const float4 a1 = *(const float4*)&xs[i1][c];
            const float4 b0 = *(const float4*)&xs[j0][c];
            const float4 b1 = *(const float4*)&xs[j1][c];
            // c-ascending chain per accumulator — bit-exact vs R5
            c00 += a0.x * b0.x; c00 += a0.y * b0.y;
            c00 += a0.z * b0.z; c00 += a0.w * b0.w;
            c01 += a0.x * b1.x; c01 += a0.y * b1.y;
            c01 += a0.z * b1.z; c01 += a0.w * b1.w;
            c10 += a1.x * b0.x; c10 += a1.y * b0.y;
            c10 += a1.z * b0.z; c10 += a1.w * b0.w;
            c11 += a1.x * b1.x; c11 += a1.y * b1.y;
            c11 += a1.z * b1.z; c11 += a1.w * b1.w;
        }
        c00 *= (1.0f / (CC - 1)); c01 *= (1.0f / (CC - 1));
        c10 *= (1.0f / (CC - 1)); c11 *= (1.0f / (CC - 1));
        covm[i0][j0] = c00; covm[i0][j1] = c01;
        covm[i1][j0] = c10; covm[i1][j1] = c11;
        covm[j0][i0] = c00; covm[j1][i0] = c01;
        covm[j0][i1] = c10; covm[j1][i1] = c11;
    }
    __syncthreads();
    if (t < KK) stdv[t] = sqrtf(covm[t][t]);
    __syncthreads();
    #pragma unroll
    for (int k = 0; k < 4; ++k) {
        const int pair = t + k * 256;
        const int i = pair >> 5, j = pair & 31;
        adj_out[(size_t)bm * 1024 + pair] = covm[i][j] / (stdv[i] * stdv[j]);
    }
}

// ---------------------------------------------------------------------------
// Kernel 2: h = gelu(A @ mean). Grid (32,4), 256 thr; wave w handles o-group
// og = bx*4+w (4 o's). A rows read with wave-uniform (scalar) addresses ->
// s_load; mr[32] per-thread registers; k-ascending chain (bit-exact vs R5).
// ---------------------------------------------------------------------------
__global__ __launch_bounds__(256) void mlp1_kernel(
    const float* __restrict__ A_ws, const float* __restrict__ mean_ws,
    float* __restrict__ h_ws)
{
    const int t  = threadIdx.x;
    const int m  = t & 63;
    const int og = blockIdx.x * 4 + __builtin_amdgcn_readfirstlane(t >> 6);
    const int b  = blockIdx.y;

    float mr[32];
    #pragma unroll
    for (int k = 0; k < 32; ++k) mr[k] = mean_ws[(size_t)(b * 32 + k) * 64 + m];

    const float* Ab = A_ws + (size_t)og * 4 * 32;   // scalar base
    #pragma unroll
    for (int q = 0; q < 4; ++q) {
        float a = 0.f;
        #pragma unroll
        for (int k = 0; k < 32; ++k) a += Ab[q * 32 + k] * mr[k];  // k-ascending
        const float g = 0.5f * a * (1.0f + erff(a * 0.70710678118654752f));
        h_ws[(size_t)(b * 512 + og * 4 + q) * 64 + m] = g;
    }
}

// ---------------------------------------------------------------------------
// Kernel 3: e = sigmoid(W2 @ h). Grid (64,4), 256 thr; wave w handles 4 o's.
// ZERO LDS: W2 addresses forced scalar (readfirstlane) -> s_load_dwordx8
// on the SMEM pipe; inner fma is v_fmac(v,s,v). h loads coalesced global.
// c-ascending chain per acc — bit-exact vs R5. e_ws layout [b][m][o].
// ---------------------------------------------------------------------------
__global__ __launch_bounds__(256) void mlp2_kernel(
    const float* __restrict__ W2, const float* __restrict__ h_ws,
    float* __restrict__ e_ws)
{
    const int t   = threadIdx.x;
    const int m   = t & 63;
    const int ol  = __builtin_amdgcn_readfirstlane((t >> 6) << 2);  // 0,4,8,12
    const int b   = blockIdx.y;
    const int ob  = blockIdx.x * 16;

    const float* w0 = W2 + (size_t)(ob + ol + 0) * 512;
    const float* w1 = W2 + (size_t)(ob + ol + 1) * 512;
    const float* w2 = W2 + (size_t)(ob + ol + 2) * 512;
    const float* w3 = W2 + (size_t)(ob + ol + 3) * 512;
    const float* hb = h_ws + (size_t)b * 512 * 64 + m;

    float a0 = 0.f, a1 = 0.f, a2 = 0.f, a3 = 0.f;
    #pragma unroll 2
    for (int c = 0; c < 512; c += 8) {
        float hv[8];
        #pragma unroll
        for (int u = 0; u < 8; ++u) hv[u] = hb[(size_t)(c + u) * 64];
        #pragma unroll
        for (int u = 0; u < 8; ++u) {
            a0 += w0[c + u] * hv[u];
            a1 += w1[c + u] * hv[u];
            a2 += w2[c + u] * hv[u];
            a3 += w3[c + u] * hv[u];
        }
    }
    float4 sv;
    sv.x = 1.0f / (1.0f + expf(-a0));
    sv.y = 1.0f / (1.0f + expf(-a1));
    sv.z = 1.0f / (1.0f + expf(-a2));
    sv.w = 1.0f / (1.0f + expf(-a3));
    *(float4*)&e_ws[(size_t)(b * 64 + m) * 1024 + ob + ol] = sv;
}

// ---------------------------------------------------------------------------
// Kernel 4: masked softmax (mask adj>0) + att @ x.  256 blocks (b,m).
// att stride 36 -> aligned float4 LDS reads (32 b128 instead of 256 b32).
// j-ascending fma chain per accumulator — bit-exact vs R5.
// ---------------------------------------------------------------------------
__global__ __launch_bounds__(256) void softmax_out_kernel(
    const float* __restrict__ x, const float* __restrict__ e_ws,
    const float* __restrict__ adj, float* __restrict__ out)
{
    __shared__ float xs[KK][260];
    __shared__ float att[KK][36];
    const int bm = blockIdx.x;
    const int b  = bm >> 6, m = bm & 63;
    const int t  = threadIdx.x;
    const float* xp = x + (size_t)bm * (KK * CC);

    #pragma unroll
    for (int s = 0; s < 8; ++s) {
        const int e = s * 1024 + t * 4;
        const float4 v = *(const float4*)(xp + e);
        *(float4*)&xs[e >> 8][e & 255] = v;
    }
    {
        const int p0 = 4 * t;
        const float4 ev4 = *(const float4*)&e_ws[(size_t)(b * 64 + m) * 1024 + p0];
        const float4 aj4 = *(const float4*)&adj[(size_t)bm * 1024 + p0];
        const int i = p0 >> 5, j0 = p0 & 31;
        float4 av;
        av.x = (aj4.x > 0.f) ? ev4.x : -INFINITY;
        av.y = (aj4.y > 0.f) ? ev4.y : -INFINITY;
        av.z = (aj4.z > 0.f) ? ev4.z : -INFINITY;
        av.w = (aj4.w > 0.f) ? ev4.w : -INFINITY;
        *(float4*)&att[i][j0] = av;
    }
    __syncthreads();
    if (t < KK) {
        float mx = -INFINITY;
        #pragma unroll
        for (int j = 0; j < KK; ++j) mx = fmaxf(mx, att[t][j]);
        float s = 0.f;
        #pragma unroll
        for (int j = 0; j < KK; ++j) {
            const float v = expf(att[t][j] - mx);
            att[t][j] = v;
            s += v;
        }
        const float inv = 1.0f / s;
        #pragma unroll
        for (int j = 0; j < KK; ++j) att[t][j] *= inv;
    }
    __syncthreads();

    const int c8 = t & 31, iq = t >> 5;
    const int i0 = iq * 4;
    const int cA = 4 * c8, cB = 128 + 4 * c8;
    float4 accA[4], accB[4];
    #pragma unroll
    for (int r = 0; r < 4; ++r) {
        accA[r] = make_float4(0.f, 0.f, 0.f, 0.f);
        accB[r] = make_float4(0.f, 0.f, 0.f, 0.f);
    }
    for (int j4 = 0; j4 < KK; j4 += 4) {
        float4 ar[4];
        #pragma unroll
        for (int r = 0; r < 4; ++r) ar[r] = *(const float4*)&att[i0 + r][j4];
        #pragma unroll
        for (int jj = 0; jj < 4; ++jj) {
            const int j = j4 + jj;
            const float4 xa = *(const float4*)&xs[j][cA];
            const float4 xb = *(const float4*)&xs[j][cB];
            #pragma unroll
            for (int r = 0; r < 4; ++r) {
                const float av = (jj == 0) ? ar[r].x :
                                 (jj == 1) ? ar[r].y :
                                 (jj == 2) ? ar[r].z : ar[r].w;
                accA[r].x += av * xa.x; accA[r].y += av * xa.y;
                accA[r].z += av * xa.z; accA[r].w += av * xa.w;
                accB[r].x += av * xb.x; accB[r].y += av * xb.y;
                accB[r].z += av * xb.z; accB[r].w += av * xb.w;
            }
        }
    }
    float* op = out + (size_t)bm * (KK * CC);
    #pragma unroll
    for (int r = 0; r < 4; ++r) {
        *(float4*)(op + (size_t)(i0 + r) * CC + cA) = accA[r];
        *(float4*)(op + (size_t)(i0 + r) * CC + cB) = accB[r];
    }
}

extern "C" void kernel_launch(void* const* d_in, const int* in_sizes, int n_in,
                              void* d_out, int out_size, void* d_ws, size_t ws_size,
                              hipStream_t stream) {
    const float* x  = (const float*)d_in[0];   // (4,64,32,256)
    const float* W1 = (const float*)d_in[1];   // (512,1024)
    const float* W2 = (const float*)d_in[2];   // (1024,512)
    float* out     = (float*)d_out;                       // 2,097,152 floats
    float* adj_out = out + (size_t)4 * 64 * 32 * 256;     // +262,144 floats

    float* A_ws    = (float*)d_ws;                 // 512*32    =  16,384
    float* mean_ws = A_ws + 16384;                 // 4*32*64   =   8,192
    float* h_ws    = mean_ws + 8192;               // 4*512*64  = 131,072
    float* e_ws    = h_ws + 131072;                // 4*64*1024 = 262,144

    stats_a_kernel<<<768, 256, 0, stream>>>(x, W1, A_ws, mean_ws, adj_out);
    mlp1_kernel<<<dim3(32, 4), 256, 0, stream>>>(A_ws, mean_ws, h_ws);
    mlp2_kernel<<<dim3(64, 4), 256, 0, stream>>>(W2, h_ws, e_ws);
    softmax_out_kernel<<<256, 256, 0, stream>>>(x, e_ws, adj_out, out);
}